// Round 1
// baseline (69.308 us; speedup 1.0000x reference)
//
#include <hip/hip_runtime.h>
#include <math.h>

#define NTH 256
#define GEPS 1e-8f

// LDS polygon storage: [buffer][vertex][tid]. Bank for [v][tid] is (2*tid)%32,
// independent of v -> conflict-free under divergent per-lane vertex indices.

__device__ __forceinline__ int clip_stage(const float2 (*src)[NTH], float2 (*dst)[NTH],
                                          int tid, int n,
                                          float ax, float ay, float bx, float by) {
    float ex = bx - ax, ey = by - ay;
    int m = 0;
    int pidx = (n > 0) ? (n - 1) : 0;
    float2 pv = src[pidx][tid];              // one dynamic-index LDS read (wrap prev)
    bool pin = (ex * (pv.y - ay) - ey * (pv.x - ax)) >= 0.0f;
#pragma unroll
    for (int i = 0; i < 8; ++i) {
        float2 cv = src[i][tid];             // static-offset LDS reads
        bool valid = i < n;
        bool cin = (ex * (cv.y - ay) - ey * (cv.x - ax)) >= 0.0f;
        if (valid && (pin != cin)) {
            float ddx = cv.x - pv.x, ddy = cv.y - pv.y;
            float t = ((ax - pv.x) * ey - (ay - pv.y) * ex) /
                      (ddx * ey - ddy * ex + GEPS);
            if (m < 8) dst[m][tid] = make_float2(pv.x + t * ddx, pv.y + t * ddy);
            m++;
        }
        if (valid && cin) {
            if (m < 8) dst[m][tid] = cv;
            m++;
        }
        pv = cv; pin = cin;
    }
    if (m > 8) m = 8;
    return (m < 3) ? 0 : m;
}

__global__ __launch_bounds__(NTH) void giou_kernel(
    const float* __restrict__ box, const float* __restrict__ tbox,
    double* __restrict__ wsum, int N)
{
    __shared__ float2 sp[2][8][NTH];   // 32 KB exactly -> 5 blocks/CU
    int tid = threadIdx.x;
    int gid = blockIdx.x * NTH + tid;

    float loss = 0.0f;
    if (gid < N) {
        const float* b1 = box  + (size_t)gid * 7;
        const float* b2 = tbox + (size_t)gid * 7;
        float cx1 = b1[0], cy1 = b1[1], w1 = expf(b1[3]), l1 = expf(b1[4]), yaw1 = b1[6];
        float cx2 = b2[0], cy2 = b2[1], w2 = expf(b2[3]), l2 = expf(b2[4]), yaw2 = b2[6];

        float s1 = sinf(yaw1), c1 = cosf(yaw1);
        float s2 = sinf(yaw2), c2 = cosf(yaw2);
        float hx1 = 0.5f * w1, hy1 = 0.5f * l1;
        float hx2 = 0.5f * w2, hy2 = 0.5f * l2;

        // CCW corners: (-dx,-dy),(dx,-dy),(dx,dy),(-dx,dy), rotated + translated
        float v1x[4], v1y[4], v2x[4], v2y[4];
        {
            const float sxs[4] = {-1.f, 1.f, 1.f, -1.f};
            const float sys[4] = {-1.f, -1.f, 1.f, 1.f};
#pragma unroll
            for (int k = 0; k < 4; ++k) {
                float xa = sxs[k] * hx1, ya = sys[k] * hy1;
                v1x[k] = xa * c1 - ya * s1 + cx1;
                v1y[k] = xa * s1 + ya * c1 + cy1;
                float xb = sxs[k] * hx2, yb = sys[k] * hy2;
                v2x[k] = xb * c2 - yb * s2 + cx2;
                v2y[k] = xb * s2 + yb * c2 + cy2;
            }
        }

        // ---- Sutherland-Hodgman: clip quad1 by the 4 edges of quad2 ----
        int n;
        {   // edge 0: input from registers (n=4), output -> sp[0]
            float ax = v2x[0], ay = v2y[0];
            float ex = v2x[1] - ax, ey = v2y[1] - ay;
            int m = 0;
            float pvx = v1x[3], pvy = v1y[3];
            bool pin = (ex * (pvy - ay) - ey * (pvx - ax)) >= 0.0f;
#pragma unroll
            for (int i = 0; i < 4; ++i) {
                float cvx = v1x[i], cvy = v1y[i];
                bool cin = (ex * (cvy - ay) - ey * (cvx - ax)) >= 0.0f;
                if (pin != cin) {
                    float ddx = cvx - pvx, ddy = cvy - pvy;
                    float t = ((ax - pvx) * ey - (ay - pvy) * ex) /
                              (ddx * ey - ddy * ex + GEPS);
                    sp[0][m][tid] = make_float2(pvx + t * ddx, pvy + t * ddy);
                    m++;
                }
                if (cin) { sp[0][m][tid] = make_float2(cvx, cvy); m++; }
                pvx = cvx; pvy = cvy; pin = cin;
            }
            n = (m < 3) ? 0 : m;
        }
        n = clip_stage(sp[0], sp[1], tid, n, v2x[1], v2y[1], v2x[2], v2y[2]);
        n = clip_stage(sp[1], sp[0], tid, n, v2x[2], v2y[2], v2x[3], v2y[3]);
        n = clip_stage(sp[0], sp[1], tid, n, v2x[3], v2y[3], v2x[0], v2y[0]);

        // ---- shoelace area of final poly (in sp[1]) ----
        float inter = 0.0f;
        if (n > 0) {
            float2 first = sp[1][0][tid];
            float2 pv = first;
            float acc = 0.0f;
#pragma unroll
            for (int i = 1; i < 8; ++i) {
                float2 cv = sp[1][i][tid];
                if (i < n) {
                    acc += pv.x * cv.y - pv.y * cv.x;
                    pv = cv;
                }
            }
            acc += pv.x * first.y - pv.y * first.x;
            inter = fabsf(acc * 0.5f);
        }

        // ---- giou ----
        float area1 = w1 * l1, area2 = w2 * l2;
        float uni = area1 + area2 - inter;
        float xmin = v1x[0], xmax = v1x[0], ymin = v1y[0], ymax = v1y[0];
#pragma unroll
        for (int k = 1; k < 4; ++k) {
            xmin = fminf(xmin, v1x[k]); xmax = fmaxf(xmax, v1x[k]);
            ymin = fminf(ymin, v1y[k]); ymax = fmaxf(ymax, v1y[k]);
        }
#pragma unroll
        for (int k = 0; k < 4; ++k) {
            xmin = fminf(xmin, v2x[k]); xmax = fmaxf(xmax, v2x[k]);
            ymin = fminf(ymin, v2y[k]); ymax = fmaxf(ymax, v2y[k]);
        }
        float enc = (xmax - xmin) * (ymax - ymin);
        float giou = inter / (uni + GEPS) - (enc - uni) / (enc + GEPS);
        loss = 1.0f - giou;
    }

    // ---- reduction: f64 wave shuffle -> block -> global atomic ----
    double v = (double)loss;
#pragma unroll
    for (int o = 32; o > 0; o >>= 1) v += __shfl_down(v, o, 64);

    __syncthreads();                      // everyone done with their LDS columns
    double* red = (double*)&sp[0][0][0];  // reuse LDS for 4 wave partials
    if ((tid & 63) == 0) red[tid >> 6] = v;
    __syncthreads();
    if (tid == 0) atomicAdd(wsum, red[0] + red[1] + red[2] + red[3]);
}

__global__ void finalize_kernel(const double* __restrict__ ws,
                                const int* __restrict__ avgp,
                                float* __restrict__ out) {
    int ib = *avgp;
    float fb = __int_as_float(ib);
    // avg_factor should be int32 per harness contract; heuristic fallback if it
    // arrived as f32 bits (an int 1e6 reinterpreted as float is a denormal).
    float av;
    if (ib > 0 && fabsf(fb) < 1e-20f) av = (float)ib;
    else av = fb;
    if (!(av >= 1.0f)) av = 1.0f;
    out[0] = (float)(*ws / (double)av);
}

extern "C" void kernel_launch(void* const* d_in, const int* in_sizes, int n_in,
                              void* d_out, int out_size, void* d_ws, size_t ws_size,
                              hipStream_t stream) {
    const float* box  = (const float*)d_in[0];
    const float* tbox = (const float*)d_in[1];
    const int*   avgp = (const int*)d_in[2];
    int N = in_sizes[0] / 7;
    double* ws = (double*)d_ws;

    hipMemsetAsync(ws, 0, sizeof(double), stream);
    int blocks = (N + NTH - 1) / NTH;
    giou_kernel<<<blocks, NTH, 0, stream>>>(box, tbox, ws, N);
    finalize_kernel<<<1, 1, 0, stream>>>(ws, avgp, (float*)d_out);
}

// Round 2
// 66.987 us; speedup vs baseline: 1.0346x; 1.0346x over previous
//
#include <hip/hip_runtime.h>
#include <math.h>

#define NTH 256
#define GEPS 1e-8f

__device__ __forceinline__ float frcp(float x) { return __builtin_amdgcn_rcpf(x); }

// LDS polygon buffer: [vertex 0..7 | 8 = drop sink][tid].
// Bank for [v][tid] is (2*tid)%32 independent of v -> conflict-free under
// divergent dynamic vertex indices. 9*256*8B = 18 KB -> 8 blocks/CU fit.

__global__ __launch_bounds__(NTH, 6) void giou_kernel(
    const float* __restrict__ box, const float* __restrict__ tbox,
    double* __restrict__ wsum, int N)
{
    __shared__ float2 sp[9][NTH];
    const int tid = threadIdx.x;
    const int gid = blockIdx.x * NTH + tid;

    float loss = 0.0f;
    if (gid < N) {
        const float* b1 = box  + (size_t)gid * 7;
        const float* b2 = tbox + (size_t)gid * 7;
        float cx1 = b1[0], cy1 = b1[1], yaw1 = b1[6];
        float cx2 = b2[0], cy2 = b2[1], yaw2 = b2[6];
        float w1 = __expf(b1[3]), l1 = __expf(b1[4]);
        float w2 = __expf(b2[3]), l2 = __expf(b2[4]);
        float s1 = __sinf(yaw1), c1 = __cosf(yaw1);
        float s2 = __sinf(yaw2), c2 = __cosf(yaw2);
        float hx1 = 0.5f * w1, hy1 = 0.5f * l1;
        float hx2 = 0.5f * w2, hy2 = 0.5f * l2;

        // CCW corners: (-dx,-dy),(dx,-dy),(dx,dy),(-dx,dy), rotated + shifted
        float v1x[4], v1y[4], v2x[4], v2y[4];
        {
            const float SX[4] = {-1.f, 1.f, 1.f, -1.f};
            const float SY[4] = {-1.f, -1.f, 1.f, 1.f};
#pragma unroll
            for (int k = 0; k < 4; ++k) {
                float xa = SX[k] * hx1, ya = SY[k] * hy1;
                v1x[k] = xa * c1 - ya * s1 + cx1;
                v1y[k] = xa * s1 + ya * c1 + cy1;
                float xb = SX[k] * hx2, yb = SY[k] * hy2;
                v2x[k] = xb * c2 - yb * s2 + cx2;
                v2y[k] = xb * s2 + yb * c2 + cy2;
            }
        }

        // encloser bbox now (frees v1 registers after stage 1)
        float xmin = v1x[0], xmax = v1x[0], ymin = v1y[0], ymax = v1y[0];
#pragma unroll
        for (int k = 1; k < 4; ++k) {
            xmin = fminf(xmin, v1x[k]); xmax = fmaxf(xmax, v1x[k]);
            ymin = fminf(ymin, v1y[k]); ymax = fmaxf(ymax, v1y[k]);
        }
#pragma unroll
        for (int k = 0; k < 4; ++k) {
            xmin = fminf(xmin, v2x[k]); xmax = fmaxf(xmax, v2x[k]);
            ymin = fminf(ymin, v2y[k]); ymax = fmaxf(ymax, v2y[k]);
        }

        // ---- stage 1: clip quad1 by edge v2[0]->v2[1], registers only ----
        // slot 2i = intersection point, slot 2i+1 = current vertex; valid bitmask
        float sx[8], sy[8];
        unsigned mask = 0;
        {
            float ax = v2x[0], ay = v2y[0];
            float ex = v2x[1] - ax, ey = v2y[1] - ay;
            float sd[4];
#pragma unroll
            for (int k = 0; k < 4; ++k)
                sd[k] = ex * (v1y[k] - ay) - ey * (v1x[k] - ax);
#pragma unroll
            for (int i = 0; i < 4; ++i) {
                int p = (i + 3) & 3;
                bool pin = sd[p] >= 0.f, cin = sd[i] >= 0.f;
                float ddx = v1x[i] - v1x[p], ddy = v1y[i] - v1y[p];
                float t = ((ax - v1x[p]) * ey - (ay - v1y[p]) * ex) *
                          frcp(ddx * ey - ddy * ex + GEPS);
                sx[2*i]   = v1x[p] + t * ddx;  sy[2*i]   = v1y[p] + t * ddy;
                sx[2*i+1] = v1x[i];            sy[2*i+1] = v1y[i];
                mask |= (unsigned)(pin != cin) << (2*i);
                mask |= (unsigned)cin          << (2*i+1);
            }
            if (__popc(mask) < 3) mask = 0;
        }

        // ---- stage 2: regs+mask -> compacted LDS ----
        int n2;
        {
            float ax = v2x[1], ay = v2y[1];
            float ex = v2x[2] - ax, ey = v2y[2] - ay;
            float pvx = sx[0], pvy = sy[0];
#pragma unroll
            for (int i = 0; i < 8; ++i) {
                bool v = (mask >> i) & 1;
                pvx = v ? sx[i] : pvx; pvy = v ? sy[i] : pvy;
            }
            bool pin = (ex * (pvy - ay) - ey * (pvx - ax)) >= 0.f;
            int m = 0;
#pragma unroll
            for (int i = 0; i < 8; ++i) {
                bool val = (mask >> i) & 1;
                bool cin = (ex * (sy[i] - ay) - ey * (sx[i] - ax)) >= 0.f;
                float ddx = sx[i] - pvx, ddy = sy[i] - pvy;
                float t = ((ax - pvx) * ey - (ay - pvy) * ex) *
                          frcp(ddx * ey - ddy * ex + GEPS);
                float ipx = pvx + t * ddx, ipy = pvy + t * ddy;
                bool eip = val && (pin != cin);
                bool ecr = val && cin;
                int r0 = eip ? (m < 8 ? m : 8) : 8;
                sp[r0][tid] = make_float2(ipx, ipy);
                m += eip ? 1 : 0;
                int r1 = ecr ? (m < 8 ? m : 8) : 8;
                sp[r1][tid] = make_float2(sx[i], sy[i]);
                m += ecr ? 1 : 0;
                pvx = val ? sx[i] : pvx; pvy = val ? sy[i] : pvy;
                pin = val ? cin : pin;
            }
            n2 = (m < 3) ? 0 : m;
        }

        // ---- stage 3: LDS -> regs (static), compact back to LDS ----
        int n3;
        {
            float rx[8], ry[8];
#pragma unroll
            for (int i = 0; i < 8; ++i) { float2 v = sp[i][tid]; rx[i] = v.x; ry[i] = v.y; }
            float ax = v2x[2], ay = v2y[2];
            float ex = v2x[3] - ax, ey = v2y[3] - ay;
            int pi = n2 - 1; pi = pi < 0 ? 0 : (pi > 7 ? 7 : pi);
            float pvx = rx[0], pvy = ry[0];
#pragma unroll
            for (int i = 1; i < 8; ++i) {
                bool h = (pi == i);
                pvx = h ? rx[i] : pvx; pvy = h ? ry[i] : pvy;
            }
            bool pin = (ex * (pvy - ay) - ey * (pvx - ax)) >= 0.f;
            int m = 0;
#pragma unroll
            for (int i = 0; i < 8; ++i) {
                bool val = i < n2;
                bool cin = (ex * (ry[i] - ay) - ey * (rx[i] - ax)) >= 0.f;
                float ddx = rx[i] - pvx, ddy = ry[i] - pvy;
                float t = ((ax - pvx) * ey - (ay - pvy) * ex) *
                          frcp(ddx * ey - ddy * ex + GEPS);
                float ipx = pvx + t * ddx, ipy = pvy + t * ddy;
                bool eip = val && (pin != cin);
                bool ecr = val && cin;
                int r0 = eip ? (m < 8 ? m : 8) : 8;
                sp[r0][tid] = make_float2(ipx, ipy);
                m += eip ? 1 : 0;
                int r1 = ecr ? (m < 8 ? m : 8) : 8;
                sp[r1][tid] = make_float2(rx[i], ry[i]);
                m += ecr ? 1 : 0;
                pvx = val ? rx[i] : pvx; pvy = val ? ry[i] : pvy;
                pin = val ? cin : pin;
            }
            n3 = (m < 3) ? 0 : m;
        }

        // ---- stage 4 fused with shoelace: emit stream -> running area ----
        float inter = 0.f;
        {
            float qx[8], qy[8];
#pragma unroll
            for (int i = 0; i < 8; ++i) { float2 v = sp[i][tid]; qx[i] = v.x; qy[i] = v.y; }
            float ax = v2x[3], ay = v2y[3];
            float ex = v2x[0] - ax, ey = v2y[0] - ay;
            int pi = n3 - 1; pi = pi < 0 ? 0 : (pi > 7 ? 7 : pi);
            float pvx = qx[0], pvy = qy[0];
#pragma unroll
            for (int i = 1; i < 8; ++i) {
                bool h = (pi == i);
                pvx = h ? qx[i] : pvx; pvy = h ? qy[i] : pvy;
            }
            bool pin = (ex * (pvy - ay) - ey * (pvx - ax)) >= 0.f;
            int j = 0;
            float fx = 0.f, fy = 0.f, px = 0.f, py = 0.f, acc = 0.f;
#pragma unroll
            for (int i = 0; i < 8; ++i) {
                bool val = i < n3;
                bool cin = (ex * (qy[i] - ay) - ey * (qx[i] - ax)) >= 0.f;
                float ddx = qx[i] - pvx, ddy = qy[i] - pvy;
                float t = ((ax - pvx) * ey - (ay - pvy) * ex) *
                          frcp(ddx * ey - ddy * ex + GEPS);
                float ipx = pvx + t * ddx, ipy = pvy + t * ddy;
                bool e1 = val && (pin != cin);
                bool e2 = val && cin;
                {   // emit intersection point
                    bool w = e1 && (j < 8);
                    float na = acc + (px * ipy - py * ipx);
                    acc = (w && j > 0) ? na : acc;
                    fx = (w && j == 0) ? ipx : fx;  fy = (w && j == 0) ? ipy : fy;
                    px = w ? ipx : px;  py = w ? ipy : py;
                    j += e1 ? 1 : 0;
                }
                {   // emit current vertex
                    bool w = e2 && (j < 8);
                    float na = acc + (px * qy[i] - py * qx[i]);
                    acc = (w && j > 0) ? na : acc;
                    fx = (w && j == 0) ? qx[i] : fx;  fy = (w && j == 0) ? qy[i] : fy;
                    px = w ? qx[i] : px;  py = w ? qy[i] : py;
                    j += e2 ? 1 : 0;
                }
                pvx = val ? qx[i] : pvx; pvy = val ? qy[i] : pvy;
                pin = val ? cin : pin;
            }
            if (j >= 3) {
                acc += px * fy - py * fx;   // wrap term
                inter = fabsf(acc * 0.5f);
            }
        }

        // ---- giou ----
        float area1 = w1 * l1, area2 = w2 * l2;
        float uni = area1 + area2 - inter;
        float enc = (xmax - xmin) * (ymax - ymin);
        float giou = inter * frcp(uni + GEPS) - (enc - uni) * frcp(enc + GEPS);
        loss = 1.0f - giou;
    }

    // ---- reduction: f64 wave shuffle -> block -> global atomic ----
    double v = (double)loss;
#pragma unroll
    for (int o = 32; o > 0; o >>= 1) v += __shfl_down(v, o, 64);

    __syncthreads();                      // done with LDS columns
    double* red = (double*)&sp[0][0];     // reuse LDS for 4 wave partials
    if ((tid & 63) == 0) red[tid >> 6] = v;
    __syncthreads();
    if (tid == 0) atomicAdd(wsum, red[0] + red[1] + red[2] + red[3]);
}

__global__ void finalize_kernel(const double* __restrict__ ws,
                                const int* __restrict__ avgp,
                                float* __restrict__ out) {
    int ib = *avgp;
    float fb = __int_as_float(ib);
    float av;
    if (ib > 0 && fabsf(fb) < 1e-20f) av = (float)ib;   // int32 payload
    else av = fb;                                        // f32 payload fallback
    if (!(av >= 1.0f)) av = 1.0f;
    out[0] = (float)(*ws / (double)av);
}

extern "C" void kernel_launch(void* const* d_in, const int* in_sizes, int n_in,
                              void* d_out, int out_size, void* d_ws, size_t ws_size,
                              hipStream_t stream) {
    const float* box  = (const float*)d_in[0];
    const float* tbox = (const float*)d_in[1];
    const int*   avgp = (const int*)d_in[2];
    int N = in_sizes[0] / 7;
    double* ws = (double*)d_ws;

    hipMemsetAsync(ws, 0, sizeof(double), stream);
    int blocks = (N + NTH - 1) / NTH;
    giou_kernel<<<blocks, NTH, 0, stream>>>(box, tbox, ws, N);
    finalize_kernel<<<1, 1, 0, stream>>>(ws, avgp, (float*)d_out);
}

// Round 3
// 33.630 us; speedup vs baseline: 2.0609x; 1.9919x over previous
//
#include <hip/hip_runtime.h>
#include <math.h>

#define NTH 256
#define GEPS 1e-8f

__device__ __forceinline__ float frcp(float x) { return __builtin_amdgcn_rcpf(x); }

// LDS polygon buffer: rows 0..7 = vertices, row 8 = drop sink.
// Bank for [v][tid] is (2*tid)%32, independent of v -> conflict-free even with
// divergent dynamic row indices. 9*256*8B = 18 KB -> 8 blocks/CU.
// Single buffer works because each stage reads ALL its input rows into
// registers before writing (DS ops are in-order per wave).

// Clip the n-vertex polygon in sp rows [0,B) by half-plane left of a->b,
// writing the compacted result back. Returns new count (<3 -> 0).
template<int B>
__device__ __forceinline__ int clip_lds(float2 (*sp)[NTH], int tid, int n,
                                        float ax, float ay, float bx, float by)
{
    float ex = bx - ax, ey = by - ay;
    float C = ex * ay - ey * ax;            // sd(p) = ex*p.y - ey*p.x - C
    float rx[B], ry[B];
#pragma unroll
    for (int i = 0; i < B; ++i) { float2 v = sp[i][tid]; rx[i] = v.x; ry[i] = v.y; }
    int npv = n - 1; if (npv < 0) npv = 0;
    float2 pvv = sp[npv][tid];              // wrap-around prev (dynamic row, conflict-free)
    float pvx = pvv.x, pvy = pvv.y;
    float sdp = fmaf(ex, pvy, -(ey * pvx)) - C;
    int m = 0;
#pragma unroll
    for (int i = 0; i < B; ++i) {
        bool val = i < n;
        float sdc = fmaf(ex, ry[i], -(ey * rx[i])) - C;
        bool cin = sdc >= 0.0f;
        bool pin = sdp >= 0.0f;
        float t = sdp * frcp(sdp - sdc + GEPS);     // == ref's t algebraically
        float ipx = fmaf(t, rx[i] - pvx, pvx);
        float ipy = fmaf(t, ry[i] - pvy, pvy);
        bool eip = val && (pin != cin);
        bool ecr = val && cin;
        int r0 = eip ? (m < 8 ? m : 8) : 8;
        sp[r0][tid] = make_float2(ipx, ipy);
        m += eip;
        int r1 = ecr ? (m < 8 ? m : 8) : 8;
        sp[r1][tid] = make_float2(rx[i], ry[i]);
        m += ecr;
        pvx = val ? rx[i] : pvx;
        pvy = val ? ry[i] : pvy;
        sdp = val ? sdc : sdp;
    }
    return (m < 3) ? 0 : m;
}

__global__ __launch_bounds__(NTH, 8) void giou_kernel(
    const float* __restrict__ box, const float* __restrict__ tbox,
    double* __restrict__ wsum, int N)
{
    __shared__ float2 sp[9][NTH];
    const int tid = threadIdx.x;
    const int gid = blockIdx.x * NTH + tid;

    float loss = 0.0f;
    if (gid < N) {
        const float* b1 = box  + (size_t)gid * 7;
        const float* b2 = tbox + (size_t)gid * 7;
        float cx1 = b1[0], cy1 = b1[1];
        float w1 = __expf(b1[3]), l1 = __expf(b1[4]);
        float yaw1 = b1[6];
        float cx2 = b2[0], cy2 = b2[1];
        float w2 = __expf(b2[3]), l2 = __expf(b2[4]);
        float yaw2 = b2[6];

        float s1 = __sinf(yaw1), c1 = __cosf(yaw1);
        float s2 = __sinf(yaw2), c2 = __cosf(yaw2);

        // half-extent vectors: u along w, v along l
        float u1x = 0.5f * w1 * c1, u1y = 0.5f * w1 * s1;
        float w1x = -0.5f * l1 * s1, w1y = 0.5f * l1 * c1;
        float u2x = 0.5f * w2 * c2, u2y = 0.5f * w2 * s2;
        float w2x = -0.5f * l2 * s2, w2y = 0.5f * l2 * c2;

        // CCW corners (-u-v, +u-v, +u+v, -u+v) + center  (matches ref order)
        float q1x[4], q1y[4], q2x[4], q2y[4];
        q1x[0] = cx1 - u1x - w1x;  q1y[0] = cy1 - u1y - w1y;
        q1x[1] = cx1 + u1x - w1x;  q1y[1] = cy1 + u1y - w1y;
        q1x[2] = cx1 + u1x + w1x;  q1y[2] = cy1 + u1y + w1y;
        q1x[3] = cx1 - u1x + w1x;  q1y[3] = cy1 - u1y + w1y;
        q2x[0] = cx2 - u2x - w2x;  q2y[0] = cy2 - u2y - w2y;
        q2x[1] = cx2 + u2x - w2x;  q2y[1] = cy2 + u2y - w2y;
        q2x[2] = cx2 + u2x + w2x;  q2y[2] = cy2 + u2y + w2y;
        q2x[3] = cx2 - u2x + w2x;  q2y[3] = cy2 - u2y + w2y;

        // enclosing bbox via extents |u|+|v| around each center
        float e1x = fabsf(u1x) + fabsf(w1x), e1y = fabsf(u1y) + fabsf(w1y);
        float e2x = fabsf(u2x) + fabsf(w2x), e2y = fabsf(u2y) + fabsf(w2y);
        float xmin = fminf(cx1 - e1x, cx2 - e2x);
        float xmax = fmaxf(cx1 + e1x, cx2 + e2x);
        float ymin = fminf(cy1 - e1y, cy2 - e2y);
        float ymax = fmaxf(cy1 + e1y, cy2 + e2y);

        // ---- stage 1: clip quad1 by edge q2[0]->q2[1] (regs -> LDS, m<=5) ----
        int n;
        {
            float ax = q2x[0], ay = q2y[0];
            float ex = q2x[1] - ax, ey = q2y[1] - ay;
            float C = ex * ay - ey * ax;
            float sd[4];
#pragma unroll
            for (int k = 0; k < 4; ++k)
                sd[k] = fmaf(ex, q1y[k], -(ey * q1x[k])) - C;
            int m = 0;
            float pvx = q1x[3], pvy = q1y[3], sdp = sd[3];
#pragma unroll
            for (int i = 0; i < 4; ++i) {
                float sdc = sd[i];
                bool cin = sdc >= 0.0f;
                bool pin = sdp >= 0.0f;
                float t = sdp * frcp(sdp - sdc + GEPS);
                float ipx = fmaf(t, q1x[i] - pvx, pvx);
                float ipy = fmaf(t, q1y[i] - pvy, pvy);
                bool eip = (pin != cin);
                int r0 = eip ? m : 8;           // m<=4 here, no extra clamp
                sp[r0][tid] = make_float2(ipx, ipy);
                m += eip;
                int r1 = cin ? m : 8;
                sp[r1][tid] = make_float2(q1x[i], q1y[i]);
                m += cin;
                pvx = q1x[i]; pvy = q1y[i]; sdp = sdc;
            }
            n = (m < 3) ? 0 : m;                // n <= 5 (quad clip bound)
        }

        // ---- stages 2,3: geometric vertex bounds 5 -> 6 -> 7 ----
        n = clip_lds<5>(sp, tid, n, q2x[1], q2y[1], q2x[2], q2y[2]);
        n = (n > 6) ? 6 : n;
        n = clip_lds<6>(sp, tid, n, q2x[2], q2y[2], q2x[3], q2y[3]);
        n = (n > 7) ? 7 : n;

        // ---- stage 4 (edge q2[3]->q2[0]) fused with shoelace ----
        float inter = 0.0f;
        {
            float ax = q2x[3], ay = q2y[3];
            float ex = q2x[0] - ax, ey = q2y[0] - ay;
            float C = ex * ay - ey * ax;
            float rx[7], ry[7];
#pragma unroll
            for (int i = 0; i < 7; ++i) { float2 v = sp[i][tid]; rx[i] = v.x; ry[i] = v.y; }
            int npv = n - 1; if (npv < 0) npv = 0;
            float2 pvv = sp[npv][tid];
            float pvx = pvv.x, pvy = pvv.y;
            float sdp = fmaf(ex, pvy, -(ey * pvx)) - C;
            int j = 0;
            float fx = 0.f, fy = 0.f, px = 0.f, py = 0.f, acc = 0.f;
#pragma unroll
            for (int i = 0; i < 7; ++i) {
                bool val = i < n;
                float sdc = fmaf(ex, ry[i], -(ey * rx[i])) - C;
                bool cin = sdc >= 0.0f;
                bool pin = sdp >= 0.0f;
                float t = sdp * frcp(sdp - sdc + GEPS);
                float ipx = fmaf(t, rx[i] - pvx, pvx);
                float ipy = fmaf(t, ry[i] - pvy, pvy);
                bool e1 = val && (pin != cin);
                bool e2 = val && cin;
                {   // emit intersection point
                    bool w = e1 && (j < 8);
                    float na = fmaf(px, ipy, -(py * ipx)) + acc;
                    acc = (w && j > 0) ? na : acc;
                    fx = (w && j == 0) ? ipx : fx;
                    fy = (w && j == 0) ? ipy : fy;
                    px = w ? ipx : px;  py = w ? ipy : py;
                    j += e1;
                }
                {   // emit current vertex
                    bool w = e2 && (j < 8);
                    float na = fmaf(px, ry[i], -(py * rx[i])) + acc;
                    acc = (w && j > 0) ? na : acc;
                    fx = (w && j == 0) ? rx[i] : fx;
                    fy = (w && j == 0) ? ry[i] : fy;
                    px = w ? rx[i] : px;  py = w ? ry[i] : py;
                    j += e2;
                }
                pvx = val ? rx[i] : pvx;
                pvy = val ? ry[i] : pvy;
                sdp = val ? sdc : sdp;
            }
            if (j >= 3) {
                acc += fmaf(px, fy, -(py * fx));   // wrap term
                inter = fabsf(acc * 0.5f);
            }
        }

        // ---- giou ----
        float area1 = w1 * l1, area2 = w2 * l2;
        float uni = area1 + area2 - inter;
        float enc = (xmax - xmin) * (ymax - ymin);
        float giou = inter * frcp(uni + GEPS) - (enc - uni) * frcp(enc + GEPS);
        loss = 1.0f - giou;
    }

    // ---- reduction: f32 wave shuffle -> f64 block partial -> spread atomics ----
    float wsf = loss;
#pragma unroll
    for (int o = 32; o > 0; o >>= 1) wsf += __shfl_down(wsf, o, 64);

    __syncthreads();                      // done with LDS columns
    double* red = (double*)&sp[0][0];     // reuse LDS for 4 wave partials
    if ((tid & 63) == 0) red[tid >> 6] = (double)wsf;
    __syncthreads();
    if (tid == 0)
        atomicAdd(&wsum[blockIdx.x & 63], red[0] + red[1] + red[2] + red[3]);
}

__global__ void finalize_kernel(const double* __restrict__ ws,
                                const int* __restrict__ avgp,
                                float* __restrict__ out) {
    double s = 0.0;
    for (int i = 0; i < 64; ++i) s += ws[i];
    int ib = *avgp;
    float fb = __int_as_float(ib);
    float av;
    if (ib > 0 && fabsf(fb) < 1e-20f) av = (float)ib;   // int32 payload
    else av = fb;                                        // f32 payload fallback
    if (!(av >= 1.0f)) av = 1.0f;
    out[0] = (float)(s / (double)av);
}

extern "C" void kernel_launch(void* const* d_in, const int* in_sizes, int n_in,
                              void* d_out, int out_size, void* d_ws, size_t ws_size,
                              hipStream_t stream) {
    const float* box  = (const float*)d_in[0];
    const float* tbox = (const float*)d_in[1];
    const int*   avgp = (const int*)d_in[2];
    int N = in_sizes[0] / 7;
    double* ws = (double*)d_ws;

    hipMemsetAsync(ws, 0, 64 * sizeof(double), stream);
    int blocks = (N + NTH - 1) / NTH;
    giou_kernel<<<blocks, NTH, 0, stream>>>(box, tbox, ws, N);
    finalize_kernel<<<1, 1, 0, stream>>>(ws, avgp, (float*)d_out);
}

// Round 4
// 30.633 us; speedup vs baseline: 2.2625x; 1.0978x over previous
//
#include <hip/hip_runtime.h>
#include <math.h>

#define NTH 256
#define GEPS 1e-8f

__device__ __forceinline__ float frcp(float x) { return __builtin_amdgcn_rcpf(x); }

// LDS polygon buffer: rows 0..7 = vertices, row 8 = drop sink.
// Bank for [v][tid] is (2*tid)%32, independent of v -> conflict-free even with
// divergent dynamic row indices. 9*256*8B = 18 KB -> 8 blocks/CU.
// Single buffer: each stage reads all inputs to regs before writing (DS in-order).

// Clip n-vertex poly in sp rows [0,B) by axis-aligned half-plane:
//   sd = NEG ? (h - coord) : (coord + h), coord = USE_X ? x : y, inside = sd>=0.
template<int B, bool USE_X, bool NEG>
__device__ __forceinline__ int clip_lds(float2 (*sp)[NTH], int tid, int n, float h)
{
    float rx[B], ry[B], sd[B];
#pragma unroll
    for (int i = 0; i < B; ++i) {
        float2 v = sp[i][tid];
        rx[i] = v.x; ry[i] = v.y;
        float c = USE_X ? v.x : v.y;
        sd[i] = NEG ? (h - c) : (c + h);
    }
    int npv = n - 1; if (npv < 0) npv = 0;
    float2 pvv = sp[npv][tid];              // wrap prev (dynamic row, conflict-free)
    float pvx = pvv.x, pvy = pvv.y;
    {
        float c = USE_X ? pvx : pvy;
        rx[0] = rx[0]; // no-op
    }
    float cp = USE_X ? pvx : pvy;
    float sdp = NEG ? (h - cp) : (cp + h);
    int m = 0;
#pragma unroll
    for (int i = 0; i < B; ++i) {
        bool val = i < n;
        float sdc = sd[i];
        bool cin = sdc >= 0.0f;
        bool pin = sdp >= 0.0f;
        float t = sdp * frcp(sdp - sdc + GEPS);   // == ref's t (EPS scale aside)
        float ipx = fmaf(t, rx[i] - pvx, pvx);
        float ipy = fmaf(t, ry[i] - pvy, pvy);
        bool eip = val && (pin != cin);
        bool ecr = val && cin;
        int r0 = eip ? (m < 8 ? m : 8) : 8;
        sp[r0][tid] = make_float2(ipx, ipy);
        m += eip;
        int r1 = ecr ? (m < 8 ? m : 8) : 8;
        sp[r1][tid] = make_float2(rx[i], ry[i]);
        m += ecr;
        pvx = val ? rx[i] : pvx;
        pvy = val ? ry[i] : pvy;
        sdp = val ? sdc : sdp;
    }
    return (m < 3) ? 0 : m;
}

__global__ __launch_bounds__(NTH, 8) void giou_kernel(
    const float* __restrict__ box, const float* __restrict__ tbox,
    double* __restrict__ wsum, int N)
{
    __shared__ float2 sp[9][NTH];
    const int tid = threadIdx.x;
    const int gid = blockIdx.x * NTH + tid;

    float loss = 0.0f;
    if (gid < N) {
        const float* b1 = box  + (size_t)gid * 7;
        const float* b2 = tbox + (size_t)gid * 7;
        float cx1 = b1[0], cy1 = b1[1];
        float w1 = __expf(b1[3]), l1 = __expf(b1[4]);
        float yaw1 = b1[6];
        float cx2 = b2[0], cy2 = b2[1];
        float w2 = __expf(b2[3]), l2 = __expf(b2[4]);
        float yaw2 = b2[6];

        float s1 = __sinf(yaw1), c1 = __cosf(yaw1);
        float s2 = __sinf(yaw2), c2 = __cosf(yaw2);
        float hx1 = 0.5f * w1, hy1 = 0.5f * l1;
        float hx2 = 0.5f * w2, hy2 = 0.5f * l2;

        // world-frame enclosing bbox via exact extent identity |u|+|v|
        // e1x = hx1*|c1| + hy1*|s1|  (abs = free input modifier)
        float e1x = fmaf(hx1, fabsf(c1), hy1 * fabsf(s1));
        float e1y = fmaf(hx1, fabsf(s1), hy1 * fabsf(c1));
        float e2x = fmaf(hx2, fabsf(c2), hy2 * fabsf(s2));
        float e2y = fmaf(hx2, fabsf(s2), hy2 * fabsf(c2));
        float xmin = fminf(cx1 - e1x, cx2 - e2x);
        float xmax = fmaxf(cx1 + e1x, cx2 + e2x);
        float ymin = fminf(cy1 - e1y, cy2 - e2y);
        float ymax = fmaxf(cy1 + e1y, cy2 + e2y);

        // ---- transform quad1 into box2's frame (box2 -> axis-aligned) ----
        float sr = s1 * c2 - c1 * s2;       // sin(yaw1-yaw2)
        float cr = c1 * c2 + s1 * s2;       // cos(yaw1-yaw2)
        float tx = cx1 - cx2, ty = cy1 - cy2;
        float dx =  c2 * tx + s2 * ty;      // R(-yaw2)*(c1-c2)
        float dy = -s2 * tx + c2 * ty;
        float ux = hx1 * cr, uy = hx1 * sr;         // R(-yaw2)*u1
        float vx = -hy1 * sr, vy = hy1 * cr;        // R(-yaw2)*v1

        // CCW corners: d-u-v, d+u-v, d+u+v, d-u+v (matches ref order)
        float qx[4], qy[4];
        qx[0] = dx - ux - vx;  qy[0] = dy - uy - vy;
        qx[1] = dx + ux - vx;  qy[1] = dy + uy - vy;
        qx[2] = dx + ux + vx;  qy[2] = dy + uy + vy;
        qx[3] = dx - ux + vx;  qy[3] = dy - uy + vy;

        // ---- stage 1: clip by edge0 (sd = y + hy2), regs -> LDS ----
        int n;
        {
            float sdv[4];
#pragma unroll
            for (int k = 0; k < 4; ++k) sdv[k] = qy[k] + hy2;
            int m = 0;
            float pvx = qx[3], pvy = qy[3], sdp = sdv[3];
#pragma unroll
            for (int i = 0; i < 4; ++i) {
                float sdc = sdv[i];
                bool cin = sdc >= 0.0f;
                bool pin = sdp >= 0.0f;
                float t = sdp * frcp(sdp - sdc + GEPS);
                float ipx = fmaf(t, qx[i] - pvx, pvx);
                float ipy = fmaf(t, qy[i] - pvy, pvy);
                bool eip = (pin != cin);
                int r0 = eip ? m : 8;            // max write index provably <=7
                sp[r0][tid] = make_float2(ipx, ipy);
                m += eip;
                int r1 = cin ? m : 8;
                sp[r1][tid] = make_float2(qx[i], qy[i]);
                m += cin;
                pvx = qx[i]; pvy = qy[i]; sdp = sdc;
            }
            n = (m < 3) ? 0 : m;                 // n <= 5 geometrically
        }
        n = (n > 5) ? 5 : n;

        // ---- stage 2: edge1 (sd = hx2 - x) ----
        n = clip_lds<5, true, true>(sp, tid, n, hx2);
        n = (n > 6) ? 6 : n;
        // ---- stage 3: edge2 (sd = hy2 - y) ----
        n = clip_lds<6, false, true>(sp, tid, n, hy2);
        n = (n > 7) ? 7 : n;

        // ---- stage 4: edge3 (sd = x + hx2), fused with shoelace ----
        float inter = 0.0f;
        {
            float rx[7], ry[7], sd[7];
#pragma unroll
            for (int i = 0; i < 7; ++i) {
                float2 v = sp[i][tid];
                rx[i] = v.x; ry[i] = v.y;
                sd[i] = v.x + hx2;
            }
            int npv = n - 1; if (npv < 0) npv = 0;
            float2 pvv = sp[npv][tid];
            float pvx = pvv.x, pvy = pvv.y;
            float sdp = pvx + hx2;
            int j = 0;
            float fx = 0.f, fy = 0.f, px = 0.f, py = 0.f, acc = 0.f;
#pragma unroll
            for (int i = 0; i < 7; ++i) {
                bool val = i < n;
                float sdc = sd[i];
                bool cin = sdc >= 0.0f;
                bool pin = sdp >= 0.0f;
                float t = sdp * frcp(sdp - sdc + GEPS);
                float ipx = fmaf(t, rx[i] - pvx, pvx);
                float ipy = fmaf(t, ry[i] - pvy, pvy);
                bool e1 = val && (pin != cin);
                bool e2 = val && cin;
                {   // emit intersection point
                    bool w = e1 && (j < 8);
                    float na = fmaf(px, ipy, -(py * ipx)) + acc;
                    acc = (w && j > 0) ? na : acc;
                    fx = (w && j == 0) ? ipx : fx;
                    fy = (w && j == 0) ? ipy : fy;
                    px = w ? ipx : px;  py = w ? ipy : py;
                    j += e1;
                }
                {   // emit current vertex
                    bool w = e2 && (j < 8);
                    float na = fmaf(px, ry[i], -(py * rx[i])) + acc;
                    acc = (w && j > 0) ? na : acc;
                    fx = (w && j == 0) ? rx[i] : fx;
                    fy = (w && j == 0) ? ry[i] : fy;
                    px = w ? rx[i] : px;  py = w ? ry[i] : py;
                    j += e2;
                }
                pvx = val ? rx[i] : pvx;
                pvy = val ? ry[i] : pvy;
                sdp = val ? sdc : sdp;
            }
            if (j >= 3) {
                acc += fmaf(px, fy, -(py * fx));   // wrap term
                inter = fabsf(acc * 0.5f);
            }
        }

        // ---- giou (union/enc in world scale; rotation preserves area) ----
        float area1 = w1 * l1, area2 = w2 * l2;
        float uni = area1 + area2 - inter;
        float enc = (xmax - xmin) * (ymax - ymin);
        float giou = inter * frcp(uni + GEPS) - (enc - uni) * frcp(enc + GEPS);
        loss = 1.0f - giou;
    }

    // ---- reduction: f32 wave shuffle -> f64 block partial -> spread atomics ----
    float wsf = loss;
#pragma unroll
    for (int o = 32; o > 0; o >>= 1) wsf += __shfl_down(wsf, o, 64);

    __syncthreads();                      // done with LDS columns
    double* red = (double*)&sp[0][0];     // reuse LDS for 4 wave partials
    if ((tid & 63) == 0) red[tid >> 6] = (double)wsf;
    __syncthreads();
    if (tid == 0)
        atomicAdd(&wsum[blockIdx.x & 63], red[0] + red[1] + red[2] + red[3]);
}

__global__ void finalize_kernel(const double* __restrict__ ws,
                                const int* __restrict__ avgp,
                                float* __restrict__ out) {
    int t = threadIdx.x;
    double v = ws[t];
#pragma unroll
    for (int o = 32; o > 0; o >>= 1) v += __shfl_down(v, o, 64);
    if (t == 0) {
        int ib = *avgp;
        float fb = __int_as_float(ib);
        float av;
        if (ib > 0 && fabsf(fb) < 1e-20f) av = (float)ib;   // int32 payload
        else av = fb;                                        // f32 payload fallback
        if (!(av >= 1.0f)) av = 1.0f;
        out[0] = (float)(v / (double)av);
    }
}

extern "C" void kernel_launch(void* const* d_in, const int* in_sizes, int n_in,
                              void* d_out, int out_size, void* d_ws, size_t ws_size,
                              hipStream_t stream) {
    const float* box  = (const float*)d_in[0];
    const float* tbox = (const float*)d_in[1];
    const int*   avgp = (const int*)d_in[2];
    int N = in_sizes[0] / 7;
    double* ws = (double*)d_ws;

    hipMemsetAsync(ws, 0, 64 * sizeof(double), stream);
    int blocks = (N + NTH - 1) / NTH;
    giou_kernel<<<blocks, NTH, 0, stream>>>(box, tbox, ws, N);
    finalize_kernel<<<1, 64, 0, stream>>>(ws, avgp, (float*)d_out);
}

// Round 5
// 29.150 us; speedup vs baseline: 2.3777x; 1.0509x over previous
//
#include <hip/hip_runtime.h>
#include <math.h>

#define NTH 256

__device__ __forceinline__ float frcp(float x) { return __builtin_amdgcn_rcpf(x); }
// reciprocal with sign-preserving epsilon: avoids Inf/NaN on degenerate edges
// (mirrors the reference's +EPS denominator; sign kept so t stays bounded)
__device__ __forceinline__ float frcp_eps(float d) {
    float es = __int_as_float((__float_as_int(d) & 0x80000000) | 0x322BCC77); // copysign(1e-8f,d)
    return __builtin_amdgcn_rcpf(d + es);
}

// LDS polygon buffer: rows 0..7 = vertices, row 8 = drop sink.
// Bank for [v][tid] is (2*tid)%32 independent of v -> conflict-free even with
// divergent dynamic row indices. 9*256*8B = 18 KB -> 8 blocks/CU.

__global__ __launch_bounds__(NTH, 8) void giou_kernel(
    const float* __restrict__ box, const float* __restrict__ tbox,
    double* __restrict__ wsum, int N)
{
    __shared__ float2 sp[9][NTH];
    const int tid = threadIdx.x;
    const int gid = blockIdx.x * NTH + tid;

    float loss = 0.0f;
    if (gid < N) {
        const float* b1 = box  + (size_t)gid * 7;
        const float* b2 = tbox + (size_t)gid * 7;
        float cx1 = b1[0], cy1 = b1[1];
        float w1 = __expf(b1[3]), l1 = __expf(b1[4]);
        float yaw1 = b1[6];
        float cx2 = b2[0], cy2 = b2[1];
        float w2 = __expf(b2[3]), l2 = __expf(b2[4]);
        float yaw2 = b2[6];

        float s1 = __sinf(yaw1), c1 = __cosf(yaw1);
        float s2 = __sinf(yaw2), c2 = __cosf(yaw2);
        float hx1 = 0.5f * w1, hy1 = 0.5f * l1;
        float hx2 = 0.5f * w2, hy2 = 0.5f * l2;

        // world-frame enclosing bbox via exact extent identity |u|+|v|
        float e1x = fmaf(hx1, fabsf(c1), hy1 * fabsf(s1));
        float e1y = fmaf(hx1, fabsf(s1), hy1 * fabsf(c1));
        float e2x = fmaf(hx2, fabsf(c2), hy2 * fabsf(s2));
        float e2y = fmaf(hx2, fabsf(s2), hy2 * fabsf(c2));
        float xmin = fminf(cx1 - e1x, cx2 - e2x);
        float xmax = fmaxf(cx1 + e1x, cx2 + e2x);
        float ymin = fminf(cy1 - e1y, cy2 - e2y);
        float ymax = fmaxf(cy1 + e1y, cy2 + e2y);

        // ---- transform quad1 into box2's frame (box2 -> axis-aligned) ----
        float sr = s1 * c2 - c1 * s2;       // sin(yaw1-yaw2)
        float cr = c1 * c2 + s1 * s2;       // cos(yaw1-yaw2)
        float tx = cx1 - cx2, ty = cy1 - cy2;
        float dxc =  c2 * tx + s2 * ty;     // R(-yaw2)*(c1-c2)
        float dyc = -s2 * tx + c2 * ty;
        float ux = hx1 * cr, uy = hx1 * sr;
        float vx = -hy1 * sr, vy = hy1 * cr;

        // CCW corners: d-u-v, d+u-v, d+u+v, d-u+v (matches ref order)
        float qx[4], qy[4];
        qx[0] = dxc - ux - vx;  qy[0] = dyc - uy - vy;
        qx[1] = dxc + ux - vx;  qy[1] = dyc + uy - vy;
        qx[2] = dxc + ux + vx;  qy[2] = dyc + uy + vy;
        qx[3] = dxc - ux + vx;  qy[3] = dyc - uy + vy;

        // ---- stage 1: clip by y-slab |y|<=hy2 (regs -> compacted LDS) ----
        // Per edge p->c: <=2 emits (two crossings XOR inside-endpoint), so
        // total <=8, write indices <=7: no clamps needed. Crossing points get
        // exact y=+-hy2. Order of two crossings follows sign(dy).
        int m = 0;
        {
            float pvx = qx[3], pvy = qy[3];
            bool pB = pvy >= -hy2, pT = pvy <= hy2;
#pragma unroll
            for (int i = 0; i < 4; ++i) {
                float cxv = qx[i], cyv = qy[i];
                bool cB = cyv >= -hy2, cT = cyv <= hy2;
                float dx = cxv - pvx, dy = cyv - pvy;
                float rd = frcp_eps(dy);
                float tB = (pvy + hy2) * (-rd);   // ~ ref t for plane y=-hy2
                float tT = (hy2 - pvy) * rd;      // ~ ref t for plane y=+hy2
                float xB = fmaf(tB, dx, pvx);
                float xT = fmaf(tT, dx, pvx);
                bool crB = pB != cB;
                bool crT = pT != cT;
                bool sw  = dy < 0.0f;             // moving down: top crossed first
                float Ax = sw ? xT : xB,  Ay = sw ?  hy2 : -hy2;
                float Bx = sw ? xB : xT,  By = sw ? -hy2 :  hy2;
                bool fA = sw ? crT : crB;
                bool fB = sw ? crB : crT;
                bool ins = cB && cT;
                int r;
                r = fA ? m : 8;  sp[r][tid] = make_float2(Ax, Ay);   m += fA;
                r = fB ? m : 8;  sp[r][tid] = make_float2(Bx, By);   m += fB;
                r = ins ? m : 8; sp[r][tid] = make_float2(cxv, cyv); m += ins;
                pvx = cxv; pvy = cyv; pB = cB; pT = cT;
            }
        }
        int n = (m < 3) ? 0 : m;   // == ref's per-stage discard (subset monotone)
        n = (n > 6) ? 6 : n;       // geometric bound: quad ∩ slab <= 6 verts

        // ---- stage 2: clip by x-slab |x|<=hx2, fused with shoelace ----
        float inter = 0.0f;
        {
            float rx[6], ry[6];
#pragma unroll
            for (int i = 0; i < 6; ++i) { float2 v = sp[i][tid]; rx[i] = v.x; ry[i] = v.y; }
            int npv = n - 1; if (npv < 0) npv = 0;
            float2 pvv = sp[npv][tid];            // wrap prev (dynamic row, conflict-free)
            float pvx = pvv.x, pvy = pvv.y;
            bool pL = pvx >= -hx2, pR = pvx <= hx2;
            int j = 0;
            float fx = 0.f, fy = 0.f, px = 0.f, py = 0.f, acc = 0.f;
#pragma unroll
            for (int i = 0; i < 6; ++i) {
                bool val = i < n;
                float cxv = rx[i], cyv = ry[i];
                bool cL = cxv >= -hx2, cR = cxv <= hx2;
                float dx = cxv - pvx, dy = cyv - pvy;
                float rd = frcp_eps(dx);
                float tL = (pvx + hx2) * (-rd);
                float tR = (hx2 - pvx) * rd;
                float yL = fmaf(tL, dy, pvy);
                float yR = fmaf(tR, dy, pvy);
                bool crL = val && (pL != cL);
                bool crR = val && (pR != cR);
                bool sw  = dx < 0.0f;             // moving left: right plane first
                float Ax = sw ?  hx2 : -hx2, Ay = sw ? yR : yL;
                float Bx = sw ? -hx2 :  hx2, By = sw ? yL : yR;
                bool fA = sw ? crR : crL;
                bool fB = sw ? crL : crR;
                bool ins = val && cL && cR;
                {   // emit A
                    float na = fmaf(px, Ay, -(py * Ax)) + acc;
                    acc = (fA && j > 0) ? na : acc;
                    bool s0 = fA && (j == 0);
                    fx = s0 ? Ax : fx;  fy = s0 ? Ay : fy;
                    px = fA ? Ax : px;  py = fA ? Ay : py;
                    j += fA;
                }
                {   // emit B
                    float na = fmaf(px, By, -(py * Bx)) + acc;
                    acc = (fB && j > 0) ? na : acc;
                    bool s0 = fB && (j == 0);
                    fx = s0 ? Bx : fx;  fy = s0 ? By : fy;
                    px = fB ? Bx : px;  py = fB ? By : py;
                    j += fB;
                }
                {   // emit C (inside endpoint)
                    float na = fmaf(px, cyv, -(py * cxv)) + acc;
                    acc = (ins && j > 0) ? na : acc;
                    bool s0 = ins && (j == 0);
                    fx = s0 ? cxv : fx;  fy = s0 ? cyv : fy;
                    px = ins ? cxv : px;  py = ins ? cyv : py;
                    j += ins;
                }
                pvx = val ? cxv : pvx;  pvy = val ? cyv : pvy;
                pL = val ? cL : pL;     pR = val ? cR : pR;
            }
            if (j >= 3) {
                acc += fmaf(px, fy, -(py * fx));   // wrap term
                inter = fabsf(acc * 0.5f);
            }
        }

        // ---- giou (areas are rotation-invariant; bbox in world frame) ----
        float area1 = w1 * l1, area2 = w2 * l2;
        float uni = area1 + area2 - inter;
        float enc = (xmax - xmin) * (ymax - ymin);
        float giou = inter * frcp(uni + 1e-8f) - (enc - uni) * frcp(enc + 1e-8f);
        loss = 1.0f - giou;
    }

    // ---- reduction: f32 wave shuffle -> f64 block partial -> spread atomics ----
    float wsf = loss;
#pragma unroll
    for (int o = 32; o > 0; o >>= 1) wsf += __shfl_down(wsf, o, 64);

    __syncthreads();                      // done with LDS columns
    double* red = (double*)&sp[0][0];     // reuse LDS for 4 wave partials
    if ((tid & 63) == 0) red[tid >> 6] = (double)wsf;
    __syncthreads();
    if (tid == 0)
        atomicAdd(&wsum[blockIdx.x & 63], red[0] + red[1] + red[2] + red[3]);
}

__global__ void finalize_kernel(const double* __restrict__ ws,
                                const int* __restrict__ avgp,
                                float* __restrict__ out) {
    int t = threadIdx.x;
    double v = ws[t];
#pragma unroll
    for (int o = 32; o > 0; o >>= 1) v += __shfl_down(v, o, 64);
    if (t == 0) {
        int ib = *avgp;
        float fb = __int_as_float(ib);
        float av;
        if (ib > 0 && fabsf(fb) < 1e-20f) av = (float)ib;   // int32 payload
        else av = fb;                                        // f32 payload fallback
        if (!(av >= 1.0f)) av = 1.0f;
        out[0] = (float)(v / (double)av);
    }
}

extern "C" void kernel_launch(void* const* d_in, const int* in_sizes, int n_in,
                              void* d_out, int out_size, void* d_ws, size_t ws_size,
                              hipStream_t stream) {
    const float* box  = (const float*)d_in[0];
    const float* tbox = (const float*)d_in[1];
    const int*   avgp = (const int*)d_in[2];
    int N = in_sizes[0] / 7;
    double* ws = (double*)d_ws;

    hipMemsetAsync(ws, 0, 64 * sizeof(double), stream);
    int blocks = (N + NTH - 1) / NTH;
    giou_kernel<<<blocks, NTH, 0, stream>>>(box, tbox, ws, N);
    finalize_kernel<<<1, 64, 0, stream>>>(ws, avgp, (float*)d_out);
}